// Round 4
// baseline (687.257 us; speedup 1.0000x reference)
//
#include <hip/hip_runtime.h>
#include <hip/hip_bf16.h>

#define DIM 128
typedef __hip_bfloat16 bf16;
typedef __attribute__((ext_vector_type(8))) short bf16x8;   // 8 bf16 = 4 VGPRs
typedef __attribute__((ext_vector_type(4))) float f32x4;

// ============================ mode detection ================================
// flagI: ==0 -> edge_index is int64 (odd 32-bit words of src half all zero)
// flagF: >128 -> x/W/b are float32, else bf16
__global__ void detect_int(const int* __restrict__ w32, int E, int* __restrict__ flagI) {
    int i = blockIdx.x * blockDim.x + threadIdx.x;
    int stride = gridDim.x * blockDim.x;
    int acc = 0;
    for (int j = i; j < E; j += stride) acc |= w32[2 * j + 1];
    if (acc) atomicOr(flagI, 1);
}

__global__ void detect_float(const unsigned short* __restrict__ xu, int* __restrict__ flagF) {
    int i = blockIdx.x * blockDim.x + threadIdx.x;   // 8192 threads
    float f = __uint_as_float(((unsigned int)xu[i]) << 16);
    float a = fabsf(f);
    bool bad = !(a <= 1e20f) || (a != 0.f && a < 1e-20f);
    if (bad) atomicAdd(flagF, 1);
}

// ============================ graph build ===================================
__global__ void count_kernel(const int* __restrict__ ei, int E,
                             const int* __restrict__ flagI, int* __restrict__ cnt) {
    int e = blockIdx.x * blockDim.x + threadIdx.x;
    if (e >= E) return;
    int d = (*flagI == 0) ? ei[2 * E + 2 * e] : ei[E + e];
    atomicAdd(&cnt[d], 1);
}

__global__ void alloc_kernel(const int* __restrict__ cnt, int* __restrict__ rowstart,
                             int* __restrict__ cursor, float* __restrict__ dis,
                             int* __restrict__ head, int N) {
    int i = blockIdx.x * blockDim.x + threadIdx.x;
    if (i >= N) return;
    int c = cnt[i];
    int s = atomicAdd(head, c);
    rowstart[i] = s;
    cursor[i] = s;
    dis[i] = rsqrtf((float)(c + 1));   // +1 self loop
}

__global__ void fill_kernel(const int* __restrict__ ei, int E,
                            const int* __restrict__ flagI,
                            int* __restrict__ cursor, int* __restrict__ csr) {
    int e = blockIdx.x * blockDim.x + threadIdx.x;
    if (e >= E) return;
    int s, d;
    if (*flagI == 0) { s = ei[2 * e]; d = ei[2 * E + 2 * e]; }
    else             { s = ei[e];     d = ei[E + e]; }
    int p = atomicAdd(&cursor[d], 1);
    csr[p] = s;
}

// ====================== W swizzle into B-fragment order =====================
// frag f = kt*8+nt holds B[k][n] for k in [kt*32,kt*32+32), n in [nt*16,nt*16+16)
// lane l supplies n = l&15, k = (l>>4)*8 + j, j=0..7 -> Wsw[(f*64+l)*8 + j]
__global__ void swizzle_w(const void* W1v, const void* W2v,
                          bf16* __restrict__ Wsw1, bf16* __restrict__ Wsw2,
                          const int* __restrict__ flagF) {
    if (*flagF > 128) return;                       // f32 mode: mfma path unused
    int id = blockIdx.x * blockDim.x + threadIdx.x; // 0..4095
    const bf16* W = (id < 2048) ? (const bf16*)W1v : (const bf16*)W2v;
    bf16* Wsw = (id < 2048) ? Wsw1 : Wsw2;
    int t = id & 2047;
    int f = t >> 6, l = t & 63;
    int kt = f >> 3, nt = f & 7;
    int q = l >> 4, m = l & 15;
    bf16 tmp[8];
    #pragma unroll
    for (int j = 0; j < 8; ++j)
        tmp[j] = W[(size_t)(kt * 32 + q * 8 + j) * DIM + nt * 16 + m];
    *(bf16x8*)(Wsw + (size_t)t * 8) = *(const bf16x8*)tmp;
}

// ============================ MFMA gemm (bf16 mode) =========================
// Y[node][c] = (X[node,:] @ W[:,c]) * dis[node]; wave = 16 nodes x 128 cols
__global__ void gemm_mfma(const bf16* __restrict__ X, const bf16* __restrict__ Wsw,
                          const float* __restrict__ dis, bf16* __restrict__ Y,
                          int N, const int* __restrict__ flagF) {
    if (*flagF > 128) return;
    int wid = threadIdx.x >> 6, lane = threadIdx.x & 63;
    int base = (blockIdx.x * 4 + wid) * 16;
    if (base + 16 > N) return;                      // N % 16 == 0 for this problem
    int m = lane & 15, q = lane >> 4;

    const bf16* xp = X + (size_t)(base + m) * DIM + q * 8;
    bf16x8 a[4];
    #pragma unroll
    for (int kt = 0; kt < 4; ++kt)
        a[kt] = *(const bf16x8*)(xp + kt * 32);

    f32x4 acc[8];
    #pragma unroll
    for (int nt = 0; nt < 8; ++nt) acc[nt] = (f32x4){0.f, 0.f, 0.f, 0.f};

    const bf16x8* bp = (const bf16x8*)Wsw;          // frag f at bp[f*64 + lane]
    #pragma unroll
    for (int kt = 0; kt < 4; ++kt) {
        #pragma unroll
        for (int nt = 0; nt < 8; ++nt) {
            bf16x8 b = bp[(size_t)(kt * 8 + nt) * 64 + lane];
            acc[nt] = __builtin_amdgcn_mfma_f32_16x16x32_bf16(a[kt], b, acc[nt], 0, 0, 0);
        }
    }
    // D: col = lane&15 (=m), row = q*4 + r
    float dr[4];
    #pragma unroll
    for (int r = 0; r < 4; ++r) dr[r] = dis[base + q * 4 + r];
    #pragma unroll
    for (int nt = 0; nt < 8; ++nt)
        #pragma unroll
        for (int r = 0; r < 4; ++r)
            Y[(size_t)(base + q * 4 + r) * DIM + nt * 16 + m] =
                __float2bfloat16(acc[nt][r] * dr[r]);
}

// f32-mode fallback gemm (never runs in bf16 mode; small grid so the no-op is cheap)
__global__ void gemm_f32(const float* __restrict__ X, const float* __restrict__ W,
                         const float* __restrict__ dis, float* __restrict__ Y,
                         int N, const int* __restrict__ flagF) {
    if (*flagF <= 128) return;
    int wid = threadIdx.x >> 6, lane = threadIdx.x & 63;
    int base = (blockIdx.x * 4 + wid) * 16;
    int end = min(base + 16, N);
    for (int n = base; n < end; ++n) {
        size_t rb = (size_t)n * DIM;
        float acc0 = 0.f, acc1 = 0.f;
        for (int k = 0; k < DIM; ++k) {
            float xv = X[rb + k];
            acc0 += xv * W[(size_t)k * DIM + lane];
            acc1 += xv * W[(size_t)k * DIM + lane + 64];
        }
        float ds = dis[n];
        Y[rb + lane] = acc0 * ds;
        Y[rb + lane + 64] = acc1 * ds;
    }
}

// ============================ aggregate =====================================
// out[node][c] = relu(dis[node]*(y[node][c] + sum_{src} y[src][c]) + b[c])
// 64 lanes/node, each lane covers channels 2c, 2c+1 (packed bf16x2 in bf16 mode)
__global__ void aggregate2(const unsigned* __restrict__ Yb, const float* __restrict__ Yf,
                           const int* __restrict__ rowstart, const int* __restrict__ cnt,
                           const int* __restrict__ csr, const float* __restrict__ dis,
                           const void* __restrict__ bias,
                           unsigned* __restrict__ Ob, float* __restrict__ Of,
                           int N, const int* __restrict__ flagF) {
    int node = blockIdx.x * 4 + (threadIdx.x >> 6);
    int c = threadIdx.x & 63;
    if (node >= N) return;
    int e0 = rowstart[node], e1 = e0 + cnt[node];
    bool f32m = (*flagF > 128);
    float a0, a1, b0, b1;
    if (!f32m) {
        unsigned u = Yb[(size_t)node * 64 + c];                 // self loop
        a0 = __uint_as_float(u << 16);
        a1 = __uint_as_float(u & 0xffff0000u);
        for (int e = e0; e < e1; ++e) {
            unsigned v = Yb[(size_t)csr[e] * 64 + c];
            a0 += __uint_as_float(v << 16);
            a1 += __uint_as_float(v & 0xffff0000u);
        }
        unsigned bb = ((const unsigned*)bias)[c];
        b0 = __uint_as_float(bb << 16);
        b1 = __uint_as_float(bb & 0xffff0000u);
    } else {
        a0 = Yf[(size_t)node * DIM + 2 * c];
        a1 = Yf[(size_t)node * DIM + 2 * c + 1];
        for (int e = e0; e < e1; ++e) {
            const float* row = Yf + (size_t)csr[e] * DIM;
            a0 += row[2 * c];
            a1 += row[2 * c + 1];
        }
        b0 = ((const float*)bias)[2 * c];
        b1 = ((const float*)bias)[2 * c + 1];
    }
    float ds = dis[node];
    float v0 = fmaxf(ds * a0 + b0, 0.f);
    float v1 = fmaxf(ds * a1 + b1, 0.f);
    if (!f32m) {
        __hip_bfloat162 h2;
        h2.x = __float2bfloat16(v0);
        h2.y = __float2bfloat16(v1);
        Ob[(size_t)node * 64 + c] = *(const unsigned*)&h2;
    } else {
        Of[(size_t)node * DIM + 2 * c] = v0;
        Of[(size_t)node * DIM + 2 * c + 1] = v1;
    }
}

// ============================ launcher ======================================
extern "C" void kernel_launch(void* const* d_in, const int* in_sizes, int n_in,
                              void* d_out, int out_size, void* d_ws, size_t ws_size,
                              hipStream_t stream) {
    const void* x  = d_in[0];
    const int*  ei = (const int*)d_in[1];
    const void* W1 = d_in[2];
    const void* b1 = d_in[3];
    const void* W2 = d_in[4];
    const void* b2 = d_in[5];

    int N = in_sizes[0] / DIM;      // 50000
    int E = in_sizes[1] / 2;        // 600000

    char* w = (char*)d_ws;
    size_t used = 0;
    auto carve = [&](size_t bytes) {
        char* p = w + used;
        used += (bytes + 255) & ~(size_t)255;
        return p;
    };
    int*   misc     = (int*)  carve(256);               // [0]=head [1]=flagI [2]=flagF
    int*   cnt      = (int*)  carve((size_t)N * 4);     // adjacent to misc (one memset)
    int*   rowstart = (int*)  carve((size_t)N * 4);
    int*   cursor   = (int*)  carve((size_t)N * 4);
    int*   csr      = (int*)  carve((size_t)E * 4);
    float* dis      = (float*)carve((size_t)N * 4);

    size_t bbuf = (size_t)N * DIM * 2;                  // 12.8 MB
    size_t fbuf = (size_t)N * DIM * 4;                  // 25.6 MB
    // union region: bf16 mode {yb, hb, Wsw1, Wsw2} aliases f32 mode {yf, hf}
    char* ub = carve(2 * fbuf);
    bf16*  ybuf_b = (bf16*)ub;
    bf16*  hbuf_b = (bf16*)(ub + bbuf);
    bf16*  Wsw1   = (bf16*)(ub + 2 * bbuf);
    bf16*  Wsw2   = (bf16*)(ub + 2 * bbuf + (size_t)DIM * DIM * 2);
    float* ybuf_f = (float*)ub;
    float* hbuf_f = (float*)(ub + fbuf);

    int* head  = misc + 0;
    int* flagI = misc + 1;
    int* flagF = misc + 2;

    hipMemsetAsync(misc, 0, 256 + (size_t)N * 4, stream);   // head/flags + cnt

    detect_int  <<<64, 256, 0, stream>>>(ei, E, flagI);
    detect_float<<<32, 256, 0, stream>>>((const unsigned short*)x, flagF);
    count_kernel<<<(E + 255) / 256, 256, 0, stream>>>(ei, E, flagI, cnt);
    alloc_kernel<<<(N + 255) / 256, 256, 0, stream>>>(cnt, rowstart, cursor, dis, head, N);
    fill_kernel <<<(E + 255) / 256, 256, 0, stream>>>(ei, E, flagI, cursor, csr);
    swizzle_w   <<<16, 256, 0, stream>>>(W1, W2, Wsw1, Wsw2, flagF);

    int tiles   = (N + 15) / 16;
    int gblocks = (tiles + 3) / 4;          // 782
    int ablocks = (N + 3) / 4;              // 12500

    // layer 1
    gemm_mfma<<<gblocks, 256, 0, stream>>>((const bf16*)x, Wsw1, dis, ybuf_b, N, flagF);
    gemm_f32 <<<gblocks, 256, 0, stream>>>((const float*)x, (const float*)W1, dis, ybuf_f, N, flagF);
    aggregate2<<<ablocks, 256, 0, stream>>>((const unsigned*)ybuf_b, ybuf_f, rowstart, cnt,
                                            csr, dis, b1, (unsigned*)hbuf_b, hbuf_f, N, flagF);
    // layer 2
    gemm_mfma<<<gblocks, 256, 0, stream>>>(hbuf_b, Wsw2, dis, ybuf_b, N, flagF);
    gemm_f32 <<<gblocks, 256, 0, stream>>>(hbuf_f, (const float*)W2, dis, ybuf_f, N, flagF);
    aggregate2<<<ablocks, 256, 0, stream>>>((const unsigned*)ybuf_b, ybuf_f, rowstart, cnt,
                                            csr, dis, b2, (unsigned*)d_out, (float*)d_out,
                                            N, flagF);
}

// Round 5
// 325.578 us; speedup vs baseline: 2.1109x; 2.1109x over previous
//
#include <hip/hip_runtime.h>
#include <hip/hip_bf16.h>

#define DIM 128
typedef __hip_bfloat16 bf16;
typedef __attribute__((ext_vector_type(8))) short bf16x8;   // 8 bf16 = 4 VGPRs
typedef __attribute__((ext_vector_type(4))) float f32x4;

// ============================ int-width detection ===========================
// flagI: ==0 -> edge_index is int64 (odd 32-bit words of src half all zero)
__global__ void detect_int(const int* __restrict__ w32, int E, int* __restrict__ flagI) {
    int i = blockIdx.x * blockDim.x + threadIdx.x;
    int stride = gridDim.x * blockDim.x;
    int acc = 0;
    for (int j = i; j < E; j += stride) acc |= w32[2 * j + 1];
    if (acc) atomicOr(flagI, 1);
}

// ============================ graph build ===================================
__global__ void count_kernel(const int* __restrict__ ei, int E,
                             const int* __restrict__ flagI, int* __restrict__ cnt) {
    int e = blockIdx.x * blockDim.x + threadIdx.x;
    if (e >= E) return;
    int d = (*flagI == 0) ? ei[2 * E + 2 * e] : ei[E + e];
    atomicAdd(&cnt[d], 1);
}

__global__ void alloc_kernel(const int* __restrict__ cnt, int* __restrict__ rowstart,
                             int* __restrict__ cursor, float* __restrict__ dis,
                             int* __restrict__ head, int N) {
    int i = blockIdx.x * blockDim.x + threadIdx.x;
    if (i >= N) return;
    int c = cnt[i];
    int s = atomicAdd(head, c);
    rowstart[i] = s;
    cursor[i] = s;
    dis[i] = rsqrtf((float)(c + 1));   // +1 self loop
}

__global__ void fill_kernel(const int* __restrict__ ei, int E,
                            const int* __restrict__ flagI,
                            int* __restrict__ cursor, int* __restrict__ csr) {
    int e = blockIdx.x * blockDim.x + threadIdx.x;
    if (e >= E) return;
    int s, d;
    if (*flagI == 0) { s = ei[2 * e]; d = ei[2 * E + 2 * e]; }
    else             { s = ei[e];     d = ei[E + e]; }
    int p = atomicAdd(&cursor[d], 1);
    csr[p] = s;
}

// ============================ dtype prep ====================================
// x: f32 -> bf16 row-major (4 elems/thread)
__global__ void cast_x(const float* __restrict__ X, bf16* __restrict__ Xb, int n4) {
    int i = blockIdx.x * blockDim.x + threadIdx.x;
    if (i >= n4) return;
    float4 v = ((const float4*)X)[i];
    bf16 t[4] = {__float2bfloat16(v.x), __float2bfloat16(v.y),
                 __float2bfloat16(v.z), __float2bfloat16(v.w)};
    ((uint2*)Xb)[i] = *(const uint2*)t;
}

// W (f32 row-major [k][n]) -> bf16 B-fragment order.
// frag f = kt*8+nt holds B[k][n], k in [kt*32,kt*32+32), n in [nt*16,nt*16+16)
// lane l supplies n = l&15, k = (l>>4)*8 + j -> Wsw[(f*64+l)*8 + j]
__global__ void swizzle_w(const float* __restrict__ W1, const float* __restrict__ W2,
                          bf16* __restrict__ Wsw1, bf16* __restrict__ Wsw2) {
    int id = blockIdx.x * blockDim.x + threadIdx.x; // 0..4095
    const float* W = (id < 2048) ? W1 : W2;
    bf16* Wsw = (id < 2048) ? Wsw1 : Wsw2;
    int t = id & 2047;
    int f = t >> 6, l = t & 63;
    int kt = f >> 3, nt = f & 7;
    int q = l >> 4, m = l & 15;
    bf16 tmp[8];
    #pragma unroll
    for (int j = 0; j < 8; ++j)
        tmp[j] = __float2bfloat16(W[(size_t)(kt * 32 + q * 8 + j) * DIM + nt * 16 + m]);
    *(bf16x8*)(Wsw + (size_t)t * 8) = *(const bf16x8*)tmp;
}

// ============================ MFMA gemm =====================================
// Y[node][c] = bf16( (X[node,:] @ W[:,c]) * dis[node] ); wave = 16 nodes x 128 cols
__global__ void gemm_mfma(const bf16* __restrict__ X, const bf16* __restrict__ Wsw,
                          const float* __restrict__ dis, bf16* __restrict__ Y, int N) {
    int wid = threadIdx.x >> 6, lane = threadIdx.x & 63;
    int base = (blockIdx.x * 4 + wid) * 16;
    if (base + 16 > N) return;                      // N % 16 == 0 here
    int m = lane & 15, q = lane >> 4;

    const bf16* xp = X + (size_t)(base + m) * DIM + q * 8;
    bf16x8 a[4];
    #pragma unroll
    for (int kt = 0; kt < 4; ++kt)
        a[kt] = *(const bf16x8*)(xp + kt * 32);     // A[m][k = kt*32 + q*8 + j]

    f32x4 acc[8];
    #pragma unroll
    for (int nt = 0; nt < 8; ++nt) acc[nt] = (f32x4){0.f, 0.f, 0.f, 0.f};

    const bf16x8* bp = (const bf16x8*)Wsw;          // frag f at bp[f*64 + lane]
    #pragma unroll
    for (int kt = 0; kt < 4; ++kt) {
        #pragma unroll
        for (int nt = 0; nt < 8; ++nt) {
            bf16x8 b = bp[(size_t)(kt * 8 + nt) * 64 + lane];
            acc[nt] = __builtin_amdgcn_mfma_f32_16x16x32_bf16(a[kt], b, acc[nt], 0, 0, 0);
        }
    }
    // D: row (node) = q*4 + r, col (channel) = nt*16 + m   [m89/m91-verified]
    float dr[4];
    #pragma unroll
    for (int r = 0; r < 4; ++r) dr[r] = dis[base + q * 4 + r];
    #pragma unroll
    for (int nt = 0; nt < 8; ++nt)
        #pragma unroll
        for (int r = 0; r < 4; ++r)
            Y[(size_t)(base + q * 4 + r) * DIM + nt * 16 + m] =
                __float2bfloat16(acc[nt][r] * dr[r]);
}

// ============================ aggregate =====================================
// out[node][c] = relu(dis[node]*(y[node][c] + sum_{src} y[src][c]) + b[c])
// 64 lanes/node; lane covers channels 2c,2c+1 packed in one uint (bf16x2)
template <bool FINAL>
__global__ void aggregate_bf(const unsigned* __restrict__ Y, const int* __restrict__ rowstart,
                             const int* __restrict__ cnt, const int* __restrict__ csr,
                             const float* __restrict__ dis, const float* __restrict__ bias,
                             unsigned* __restrict__ Hb, float2* __restrict__ Of, int N) {
    int node = blockIdx.x * 4 + (threadIdx.x >> 6);
    int c = threadIdx.x & 63;
    if (node >= N) return;
    int e0 = rowstart[node], e1 = e0 + cnt[node];
    unsigned u = Y[(size_t)node * 64 + c];                 // self loop
    float a0 = __uint_as_float(u << 16);
    float a1 = __uint_as_float(u & 0xffff0000u);
    for (int e = e0; e < e1; ++e) {
        unsigned v = Y[(size_t)csr[e] * 64 + c];
        a0 += __uint_as_float(v << 16);
        a1 += __uint_as_float(v & 0xffff0000u);
    }
    float2 b = ((const float2*)bias)[c];
    float ds = dis[node];
    float v0 = fmaxf(ds * a0 + b.x, 0.f);
    float v1 = fmaxf(ds * a1 + b.y, 0.f);
    if (FINAL) {
        Of[(size_t)node * 64 + c] = make_float2(v0, v1);
    } else {
        bf16 t[2] = {__float2bfloat16(v0), __float2bfloat16(v1)};
        Hb[(size_t)node * 64 + c] = *(const unsigned*)t;
    }
}

// ============================ launcher ======================================
extern "C" void kernel_launch(void* const* d_in, const int* in_sizes, int n_in,
                              void* d_out, int out_size, void* d_ws, size_t ws_size,
                              hipStream_t stream) {
    const float* x  = (const float*)d_in[0];
    const int*   ei = (const int*)d_in[1];
    const float* W1 = (const float*)d_in[2];
    const float* b1 = (const float*)d_in[3];
    const float* W2 = (const float*)d_in[4];
    const float* b2 = (const float*)d_in[5];

    int N = in_sizes[0] / DIM;      // 50000
    int E = in_sizes[1] / 2;        // 600000

    char* w = (char*)d_ws;
    size_t used = 0;
    auto carve = [&](size_t bytes) {
        char* p = w + used;
        used += (bytes + 255) & ~(size_t)255;
        return p;
    };
    int*   misc     = (int*)  carve(256);               // [0]=head [1]=flagI
    int*   cnt      = (int*)  carve((size_t)N * 4);     // adjacent to misc (one memset)
    int*   rowstart = (int*)  carve((size_t)N * 4);
    int*   cursor   = (int*)  carve((size_t)N * 4);
    int*   csr      = (int*)  carve((size_t)E * 4);
    float* dis      = (float*)carve((size_t)N * 4);
    bf16*  xb       = (bf16*) carve((size_t)N * DIM * 2);
    bf16*  ybuf     = (bf16*) carve((size_t)N * DIM * 2);
    bf16*  hbuf     = (bf16*) carve((size_t)N * DIM * 2);
    bf16*  Wsw1     = (bf16*) carve((size_t)DIM * DIM * 2);
    bf16*  Wsw2     = (bf16*) carve((size_t)DIM * DIM * 2);

    int* head  = misc + 0;
    int* flagI = misc + 1;

    hipMemsetAsync(misc, 0, 256 + (size_t)N * 4, stream);   // head/flag + cnt

    detect_int  <<<64, 256, 0, stream>>>(ei, E, flagI);
    count_kernel<<<(E + 255) / 256, 256, 0, stream>>>(ei, E, flagI, cnt);
    alloc_kernel<<<(N + 255) / 256, 256, 0, stream>>>(cnt, rowstart, cursor, dis, head, N);
    fill_kernel <<<(E + 255) / 256, 256, 0, stream>>>(ei, E, flagI, cursor, csr);

    int n4 = N * DIM / 4;
    cast_x   <<<(n4 + 255) / 256, 256, 0, stream>>>(x, xb, n4);
    swizzle_w<<<16, 256, 0, stream>>>(W1, W2, Wsw1, Wsw2);

    int tiles   = (N + 15) / 16;
    int gblocks = (tiles + 3) / 4;          // 782
    int ablocks = (N + 3) / 4;              // 12500

    // layer 1
    gemm_mfma<<<gblocks, 256, 0, stream>>>(xb, Wsw1, dis, ybuf, N);
    aggregate_bf<false><<<ablocks, 256, 0, stream>>>((const unsigned*)ybuf, rowstart, cnt,
                                                     csr, dis, b1, (unsigned*)hbuf, nullptr, N);
    // layer 2
    gemm_mfma<<<gblocks, 256, 0, stream>>>(hbuf, Wsw2, dis, ybuf, N);
    aggregate_bf<true><<<ablocks, 256, 0, stream>>>((const unsigned*)ybuf, rowstart, cnt,
                                                    csr, dis, b2, nullptr, (float2*)d_out, N);
}

// Round 6
// 261.830 us; speedup vs baseline: 2.6248x; 1.2435x over previous
//
#include <hip/hip_runtime.h>
#include <hip/hip_bf16.h>

#define DIM 128
typedef __hip_bfloat16 bf16;
typedef __attribute__((ext_vector_type(8))) short bf16x8;   // 8 bf16 = 4 VGPRs
typedef __attribute__((ext_vector_type(4))) float f32x4;

// ============================ int-width detection ===========================
// flagI: ==0 -> edge_index is int64 (odd 32-bit words of src half all zero)
__global__ void detect_int(const int* __restrict__ w32, int E, int* __restrict__ flagI) {
    int i = blockIdx.x * blockDim.x + threadIdx.x;
    int stride = gridDim.x * blockDim.x;
    int acc = 0;
    for (int j = i; j < E; j += stride) acc |= w32[2 * j + 1];
    if (acc) atomicOr(flagI, 1);
}

// ============================ graph build ===================================
__global__ void count_kernel(const int* __restrict__ ei, int E,
                             const int* __restrict__ flagI, int* __restrict__ cnt) {
    int e = blockIdx.x * blockDim.x + threadIdx.x;
    if (e >= E) return;
    int d = (*flagI == 0) ? ei[2 * E + 2 * e] : ei[E + e];
    atomicAdd(&cnt[d], 1);
}

__global__ void alloc_kernel(const int* __restrict__ cnt, int* __restrict__ rowstart,
                             int* __restrict__ cursor, float* __restrict__ dis,
                             int* __restrict__ head, int N) {
    int i = blockIdx.x * blockDim.x + threadIdx.x;
    if (i >= N) return;
    int c = cnt[i];
    int s = atomicAdd(head, c);
    rowstart[i] = s;
    cursor[i] = s;
    dis[i] = rsqrtf((float)(c + 1));   // +1 self loop
}

__global__ void fill_kernel(const int* __restrict__ ei, int E,
                            const int* __restrict__ flagI,
                            int* __restrict__ cursor, int* __restrict__ csr) {
    int e = blockIdx.x * blockDim.x + threadIdx.x;
    if (e >= E) return;
    int s, d;
    if (*flagI == 0) { s = ei[2 * e]; d = ei[2 * E + 2 * e]; }
    else             { s = ei[e];     d = ei[E + e]; }
    int p = atomicAdd(&cursor[d], 1);
    csr[p] = s;
}

// ============================ weight swizzle ================================
// W (f32 row-major [k][n]) -> bf16 B-fragment order.
// frag f = kt*8+nt holds B[k][n], k in [kt*32,kt*32+32), n in [nt*16,nt*16+16)
// lane l supplies n = l&15, k = (l>>4)*8 + j -> Wsw[(f*64+l)*8 + j]
__global__ void swizzle_w(const float* __restrict__ W1, const float* __restrict__ W2,
                          bf16* __restrict__ Wsw1, bf16* __restrict__ Wsw2) {
    int id = blockIdx.x * blockDim.x + threadIdx.x; // 0..4095
    const float* W = (id < 2048) ? W1 : W2;
    bf16* Wsw = (id < 2048) ? Wsw1 : Wsw2;
    int t = id & 2047;
    int f = t >> 6, l = t & 63;
    int kt = f >> 3, nt = f & 7;
    int q = l >> 4, m = l & 15;
    bf16 tmp[8];
    #pragma unroll
    for (int j = 0; j < 8; ++j)
        tmp[j] = __float2bfloat16(W[(size_t)(kt * 32 + q * 8 + j) * DIM + nt * 16 + m]);
    *(bf16x8*)(Wsw + (size_t)t * 8) = *(const bf16x8*)tmp;
}

// ============================ MFMA gemm =====================================
// Y[node][c] = bf16( (X[node,:] @ W[:,c]) * dis[node] ); wave = 16 nodes x 128 cols
// XF32: layer-1 variant loads f32 X and converts in-register (cast fused).
template <bool XF32>
__global__ void gemm_mfma(const void* __restrict__ Xv, const bf16* __restrict__ Wsw,
                          const float* __restrict__ dis, bf16* __restrict__ Y, int N) {
    int wid = threadIdx.x >> 6, lane = threadIdx.x & 63;
    int base = (blockIdx.x * 4 + wid) * 16;
    if (base + 16 > N) return;                      // N % 16 == 0 here
    int m = lane & 15, q = lane >> 4;

    bf16x8 a[4];
    if (XF32) {
        const float* xp = (const float*)Xv + (size_t)(base + m) * DIM + q * 8;
        #pragma unroll
        for (int kt = 0; kt < 4; ++kt) {
            float4 v0 = *(const float4*)(xp + kt * 32);
            float4 v1 = *(const float4*)(xp + kt * 32 + 4);
            bf16 t[8] = {__float2bfloat16(v0.x), __float2bfloat16(v0.y),
                         __float2bfloat16(v0.z), __float2bfloat16(v0.w),
                         __float2bfloat16(v1.x), __float2bfloat16(v1.y),
                         __float2bfloat16(v1.z), __float2bfloat16(v1.w)};
            a[kt] = *(const bf16x8*)t;
        }
    } else {
        const bf16* xp = (const bf16*)Xv + (size_t)(base + m) * DIM + q * 8;
        #pragma unroll
        for (int kt = 0; kt < 4; ++kt)
            a[kt] = *(const bf16x8*)(xp + kt * 32);  // A[m][k = kt*32 + q*8 + j]
    }

    f32x4 acc[8];
    #pragma unroll
    for (int nt = 0; nt < 8; ++nt) acc[nt] = (f32x4){0.f, 0.f, 0.f, 0.f};

    const bf16x8* bp = (const bf16x8*)Wsw;          // frag f at bp[f*64 + lane]
    #pragma unroll
    for (int kt = 0; kt < 4; ++kt) {
        #pragma unroll
        for (int nt = 0; nt < 8; ++nt) {
            bf16x8 b = bp[(size_t)(kt * 8 + nt) * 64 + lane];
            acc[nt] = __builtin_amdgcn_mfma_f32_16x16x32_bf16(a[kt], b, acc[nt], 0, 0, 0);
        }
    }
    // D: row (node) = q*4 + r, col (channel) = nt*16 + m   [m89/m91-verified]
    float dr[4];
    #pragma unroll
    for (int r = 0; r < 4; ++r) dr[r] = dis[base + q * 4 + r];
    #pragma unroll
    for (int nt = 0; nt < 8; ++nt)
        #pragma unroll
        for (int r = 0; r < 4; ++r)
            Y[(size_t)(base + q * 4 + r) * DIM + nt * 16 + m] =
                __float2bfloat16(acc[nt][r] * dr[r]);
}

// ============================ aggregate =====================================
// out[node][c] = relu(dis[node]*(y[node][c] + sum_{src} y[src][c]) + b[c])
// 64 lanes/node; lane covers channels 2c,2c+1 packed in one uint (bf16x2).
// Edge loop unrolled x4 with independent accumulators for memory-level parallelism.
__device__ __forceinline__ void bfacc(float& lo, float& hi, unsigned v) {
    lo += __uint_as_float(v << 16);
    hi += __uint_as_float(v & 0xffff0000u);
}

template <bool FINAL>
__global__ void aggregate_bf(const unsigned* __restrict__ Y, const int* __restrict__ rowstart,
                             const int* __restrict__ cnt, const int* __restrict__ csr,
                             const float* __restrict__ dis, const float* __restrict__ bias,
                             unsigned* __restrict__ Hb, float2* __restrict__ Of, int N) {
    int node = blockIdx.x * 4 + (threadIdx.x >> 6);
    int c = threadIdx.x & 63;
    if (node >= N) return;
    int e0 = rowstart[node], cn = cnt[node];
    int e1 = e0 + cn;

    float a0 = 0.f, a1 = 0.f, b0 = 0.f, b1 = 0.f;
    float c0 = 0.f, c1 = 0.f, d0 = 0.f, d1 = 0.f;
    bfacc(a0, a1, Y[(size_t)node * 64 + c]);            // self loop

    int e = e0;
    for (; e + 4 <= e1; e += 4) {
        int s0 = csr[e], s1 = csr[e + 1], s2 = csr[e + 2], s3 = csr[e + 3];
        unsigned v0 = Y[(size_t)s0 * 64 + c];
        unsigned v1 = Y[(size_t)s1 * 64 + c];
        unsigned v2 = Y[(size_t)s2 * 64 + c];
        unsigned v3 = Y[(size_t)s3 * 64 + c];
        bfacc(a0, a1, v0);
        bfacc(b0, b1, v1);
        bfacc(c0, c1, v2);
        bfacc(d0, d1, v3);
    }
    for (; e < e1; ++e)
        bfacc(a0, a1, Y[(size_t)csr[e] * 64 + c]);

    float s0 = (a0 + b0) + (c0 + d0);
    float s1 = (a1 + b1) + (c1 + d1);
    float2 b = ((const float2*)bias)[c];
    float ds = dis[node];
    float v0 = fmaxf(ds * s0 + b.x, 0.f);
    float v1 = fmaxf(ds * s1 + b.y, 0.f);
    if (FINAL) {
        Of[(size_t)node * 64 + c] = make_float2(v0, v1);
    } else {
        bf16 t[2] = {__float2bfloat16(v0), __float2bfloat16(v1)};
        Hb[(size_t)node * 64 + c] = *(const unsigned*)t;
    }
}

// ============================ launcher ======================================
extern "C" void kernel_launch(void* const* d_in, const int* in_sizes, int n_in,
                              void* d_out, int out_size, void* d_ws, size_t ws_size,
                              hipStream_t stream) {
    const float* x  = (const float*)d_in[0];
    const int*   ei = (const int*)d_in[1];
    const float* W1 = (const float*)d_in[2];
    const float* b1 = (const float*)d_in[3];
    const float* W2 = (const float*)d_in[4];
    const float* b2 = (const float*)d_in[5];

    int N = in_sizes[0] / DIM;      // 50000
    int E = in_sizes[1] / 2;        // 600000

    char* w = (char*)d_ws;
    size_t used = 0;
    auto carve = [&](size_t bytes) {
        char* p = w + used;
        used += (bytes + 255) & ~(size_t)255;
        return p;
    };
    int*   misc     = (int*)  carve(256);               // [0]=head [1]=flagI
    int*   cnt      = (int*)  carve((size_t)N * 4);     // adjacent to misc (one memset)
    int*   rowstart = (int*)  carve((size_t)N * 4);
    int*   cursor   = (int*)  carve((size_t)N * 4);
    int*   csr      = (int*)  carve((size_t)E * 4);
    float* dis      = (float*)carve((size_t)N * 4);
    bf16*  ybuf     = (bf16*) carve((size_t)N * DIM * 2);
    bf16*  hbuf     = (bf16*) carve((size_t)N * DIM * 2);
    bf16*  Wsw1     = (bf16*) carve((size_t)DIM * DIM * 2);
    bf16*  Wsw2     = (bf16*) carve((size_t)DIM * DIM * 2);

    int* head  = misc + 0;
    int* flagI = misc + 1;

    hipMemsetAsync(misc, 0, 256 + (size_t)N * 4, stream);   // head/flag + cnt

    detect_int  <<<64, 256, 0, stream>>>(ei, E, flagI);
    count_kernel<<<(E + 255) / 256, 256, 0, stream>>>(ei, E, flagI, cnt);
    alloc_kernel<<<(N + 255) / 256, 256, 0, stream>>>(cnt, rowstart, cursor, dis, head, N);
    fill_kernel <<<(E + 255) / 256, 256, 0, stream>>>(ei, E, flagI, cursor, csr);
    swizzle_w   <<<16, 256, 0, stream>>>(W1, W2, Wsw1, Wsw2);

    int tiles   = (N + 15) / 16;
    int gblocks = (tiles + 3) / 4;          // 782
    int ablocks = (N + 3) / 4;              // 12500

    // layer 1 (cast fused into the gemm: reads f32 x directly)
    gemm_mfma<true><<<gblocks, 256, 0, stream>>>(x, Wsw1, dis, ybuf, N);
    aggregate_bf<false><<<ablocks, 256, 0, stream>>>((const unsigned*)ybuf, rowstart, cnt,
                                                     csr, dis, b1, (unsigned*)hbuf, nullptr, N);
    // layer 2
    gemm_mfma<false><<<gblocks, 256, 0, stream>>>(hbuf, Wsw2, dis, ybuf, N);
    aggregate_bf<true><<<ablocks, 256, 0, stream>>>((const unsigned*)ybuf, rowstart, cnt,
                                                    csr, dis, b2, nullptr, (float2*)d_out, N);
}

// Round 7
// 253.123 us; speedup vs baseline: 2.7151x; 1.0344x over previous
//
#include <hip/hip_runtime.h>
#include <hip/hip_bf16.h>

#define DIM 128
typedef __hip_bfloat16 bf16;
typedef __attribute__((ext_vector_type(8))) short bf16x8;   // 8 bf16 = 4 VGPRs
typedef __attribute__((ext_vector_type(4))) float f32x4;

// ============================ int-width detection ===========================
// flagI: ==0 -> edge_index is int64 (odd 32-bit words of src half all zero)
__global__ void detect_int(const int* __restrict__ w32, int E, int* __restrict__ flagI) {
    int i = blockIdx.x * blockDim.x + threadIdx.x;
    int stride = gridDim.x * blockDim.x;
    int acc = 0;
    for (int j = i; j < E; j += stride) acc |= w32[2 * j + 1];
    if (acc) atomicOr(flagI, 1);
}

// ============================ graph build ===================================
__global__ void count_kernel(const int* __restrict__ ei, int E,
                             const int* __restrict__ flagI, int* __restrict__ cnt) {
    int e = blockIdx.x * blockDim.x + threadIdx.x;
    if (e >= E) return;
    int d = (*flagI == 0) ? ei[2 * E + 2 * e] : ei[E + e];
    atomicAdd(&cnt[d], 1);
}

__global__ void alloc_kernel(const int* __restrict__ cnt, int* __restrict__ rowstart,
                             int* __restrict__ cursor, float* __restrict__ dis,
                             int* __restrict__ head, int N) {
    int i = blockIdx.x * blockDim.x + threadIdx.x;
    if (i >= N) return;
    int c = cnt[i];
    int s = atomicAdd(head, c);
    rowstart[i] = s;
    cursor[i] = s;
    dis[i] = rsqrtf((float)(c + 1));   // +1 self loop
}

__global__ void fill_kernel(const int* __restrict__ ei, int E,
                            const int* __restrict__ flagI,
                            int* __restrict__ cursor, int* __restrict__ csr) {
    int e = blockIdx.x * blockDim.x + threadIdx.x;
    if (e >= E) return;
    int s, d;
    if (*flagI == 0) { s = ei[2 * e]; d = ei[2 * E + 2 * e]; }
    else             { s = ei[e];     d = ei[E + e]; }
    int p = atomicAdd(&cursor[d], 1);
    csr[p] = s;
}

// ============================ weight swizzle ================================
// W (f32 row-major [k][n]) -> bf16 B-fragment order.
// frag f = kt*8+nt holds B[k][n], k in [kt*32,kt*32+32), n in [nt*16,nt*16+16)
// lane l supplies n = l&15, k = (l>>4)*8 + j -> Wsw[(f*64+l)*8 + j]
__global__ void swizzle_w(const float* __restrict__ W1, const float* __restrict__ W2,
                          bf16* __restrict__ Wsw1, bf16* __restrict__ Wsw2) {
    int id = blockIdx.x * blockDim.x + threadIdx.x; // 0..4095
    const float* W = (id < 2048) ? W1 : W2;
    bf16* Wsw = (id < 2048) ? Wsw1 : Wsw2;
    int t = id & 2047;
    int f = t >> 6, l = t & 63;
    int kt = f >> 3, nt = f & 7;
    int q = l >> 4, m = l & 15;
    bf16 tmp[8];
    #pragma unroll
    for (int j = 0; j < 8; ++j)
        tmp[j] = __float2bfloat16(W[(size_t)(kt * 32 + q * 8 + j) * DIM + nt * 16 + m]);
    *(bf16x8*)(Wsw + (size_t)t * 8) = *(const bf16x8*)tmp;
}

// ============================ MFMA gemm =====================================
// Y[node][c] = bf16( (X[node,:] @ W[:,c]) * dis[node] ); wave = 16 nodes x 128 cols
// XF32: layer-1 variant loads f32 X and converts in-register (cast fused).
template <bool XF32>
__global__ void gemm_mfma(const void* __restrict__ Xv, const bf16* __restrict__ Wsw,
                          const float* __restrict__ dis, bf16* __restrict__ Y, int N) {
    int wid = threadIdx.x >> 6, lane = threadIdx.x & 63;
    int base = (blockIdx.x * 4 + wid) * 16;
    if (base + 16 > N) return;                      // N % 16 == 0 here
    int m = lane & 15, q = lane >> 4;

    bf16x8 a[4];
    if (XF32) {
        const float* xp = (const float*)Xv + (size_t)(base + m) * DIM + q * 8;
        #pragma unroll
        for (int kt = 0; kt < 4; ++kt) {
            float4 v0 = *(const float4*)(xp + kt * 32);
            float4 v1 = *(const float4*)(xp + kt * 32 + 4);
            bf16 t[8] = {__float2bfloat16(v0.x), __float2bfloat16(v0.y),
                         __float2bfloat16(v0.z), __float2bfloat16(v0.w),
                         __float2bfloat16(v1.x), __float2bfloat16(v1.y),
                         __float2bfloat16(v1.z), __float2bfloat16(v1.w)};
            a[kt] = *(const bf16x8*)t;
        }
    } else {
        const bf16* xp = (const bf16*)Xv + (size_t)(base + m) * DIM + q * 8;
        #pragma unroll
        for (int kt = 0; kt < 4; ++kt)
            a[kt] = *(const bf16x8*)(xp + kt * 32);  // A[m][k = kt*32 + q*8 + j]
    }

    f32x4 acc[8];
    #pragma unroll
    for (int nt = 0; nt < 8; ++nt) acc[nt] = (f32x4){0.f, 0.f, 0.f, 0.f};

    const bf16x8* bp = (const bf16x8*)Wsw;          // frag f at bp[f*64 + lane]
    #pragma unroll
    for (int kt = 0; kt < 4; ++kt) {
        #pragma unroll
        for (int nt = 0; nt < 8; ++nt) {
            bf16x8 b = bp[(size_t)(kt * 8 + nt) * 64 + lane];
            acc[nt] = __builtin_amdgcn_mfma_f32_16x16x32_bf16(a[kt], b, acc[nt], 0, 0, 0);
        }
    }
    // D: row (node) = q*4 + r, col (channel) = nt*16 + m   [m89/m91-verified]
    float dr[4];
    #pragma unroll
    for (int r = 0; r < 4; ++r) dr[r] = dis[base + q * 4 + r];
    #pragma unroll
    for (int nt = 0; nt < 8; ++nt)
        #pragma unroll
        for (int r = 0; r < 4; ++r)
            Y[(size_t)(base + q * 4 + r) * DIM + nt * 16 + m] =
                __float2bfloat16(acc[nt][r] * dr[r]);
}

// ============================ aggregate =====================================
// out[node][c] = relu(dis[node]*(y[node][c] + sum_{src} y[src][c]) + b[c])
// 64 lanes/node; lane covers channels 2c,2c+1 packed in one uint (bf16x2).
// 8-deep edge unroll: 8 independent row-gathers in flight per wave (MLP).
__device__ __forceinline__ void bfacc(float& lo, float& hi, unsigned v) {
    lo += __uint_as_float(v << 16);
    hi += __uint_as_float(v & 0xffff0000u);
}

template <bool FINAL>
__global__ __launch_bounds__(256, 8)
void aggregate_bf(const unsigned* __restrict__ Y, const int* __restrict__ rowstart,
                  const int* __restrict__ cnt, const int* __restrict__ csr,
                  const float* __restrict__ dis, const float* __restrict__ bias,
                  unsigned* __restrict__ Hb, float2* __restrict__ Of, int N) {
    int node = blockIdx.x * 4 + (threadIdx.x >> 6);
    int c = threadIdx.x & 63;
    if (node >= N) return;
    int e0 = rowstart[node], e1 = e0 + cnt[node];

    float lo[8], hi[8];
    #pragma unroll
    for (int j = 0; j < 8; ++j) { lo[j] = 0.f; hi[j] = 0.f; }
    bfacc(lo[7], hi[7], Y[(size_t)node * 64 + c]);      // self loop

    int e = e0;
    while (e + 8 <= e1) {
        int s[8];
        #pragma unroll
        for (int j = 0; j < 8; ++j) s[j] = csr[e + j];
        unsigned v[8];
        #pragma unroll
        for (int j = 0; j < 8; ++j) v[j] = Y[(size_t)s[j] * 64 + c];
        #pragma unroll
        for (int j = 0; j < 8; ++j) bfacc(lo[j], hi[j], v[j]);
        e += 8;
    }
    if (e + 4 <= e1) {
        int s[4];
        #pragma unroll
        for (int j = 0; j < 4; ++j) s[j] = csr[e + j];
        unsigned v[4];
        #pragma unroll
        for (int j = 0; j < 4; ++j) v[j] = Y[(size_t)s[j] * 64 + c];
        #pragma unroll
        for (int j = 0; j < 4; ++j) bfacc(lo[j], hi[j], v[j]);
        e += 4;
    }
    for (; e < e1; ++e)
        bfacc(lo[0], hi[0], Y[(size_t)csr[e] * 64 + c]);

    float s0 = ((lo[0] + lo[1]) + (lo[2] + lo[3])) + ((lo[4] + lo[5]) + (lo[6] + lo[7]));
    float s1 = ((hi[0] + hi[1]) + (hi[2] + hi[3])) + ((hi[4] + hi[5]) + (hi[6] + hi[7]));
    float2 b = ((const float2*)bias)[c];
    float ds = dis[node];
    float v0 = fmaxf(ds * s0 + b.x, 0.f);
    float v1 = fmaxf(ds * s1 + b.y, 0.f);
    if (FINAL) {
        Of[(size_t)node * 64 + c] = make_float2(v0, v1);
    } else {
        bf16 t[2] = {__float2bfloat16(v0), __float2bfloat16(v1)};
        Hb[(size_t)node * 64 + c] = *(const unsigned*)t;
    }
}

// ============================ launcher ======================================
extern "C" void kernel_launch(void* const* d_in, const int* in_sizes, int n_in,
                              void* d_out, int out_size, void* d_ws, size_t ws_size,
                              hipStream_t stream) {
    const float* x  = (const float*)d_in[0];
    const int*   ei = (const int*)d_in[1];
    const float* W1 = (const float*)d_in[2];
    const float* b1 = (const float*)d_in[3];
    const float* W2 = (const float*)d_in[4];
    const float* b2 = (const float*)d_in[5];

    int N = in_sizes[0] / DIM;      // 50000
    int E = in_sizes[1] / 2;        // 600000

    char* w = (char*)d_ws;
    size_t used = 0;
    auto carve = [&](size_t bytes) {
        char* p = w + used;
        used += (bytes + 255) & ~(size_t)255;
        return p;
    };
    int*   misc     = (int*)  carve(256);               // [0]=head [1]=flagI
    int*   cnt      = (int*)  carve((size_t)N * 4);     // adjacent to misc (one memset)
    int*   rowstart = (int*)  carve((size_t)N * 4);
    int*   cursor   = (int*)  carve((size_t)N * 4);
    int*   csr      = (int*)  carve((size_t)E * 4);
    float* dis      = (float*)carve((size_t)N * 4);
    bf16*  ybuf     = (bf16*) carve((size_t)N * DIM * 2);
    bf16*  hbuf     = (bf16*) carve((size_t)N * DIM * 2);
    bf16*  Wsw1     = (bf16*) carve((size_t)DIM * DIM * 2);
    bf16*  Wsw2     = (bf16*) carve((size_t)DIM * DIM * 2);

    int* head  = misc + 0;
    int* flagI = misc + 1;

    hipMemsetAsync(misc, 0, 256 + (size_t)N * 4, stream);   // head/flag + cnt

    detect_int  <<<64, 256, 0, stream>>>(ei, E, flagI);
    count_kernel<<<(E + 255) / 256, 256, 0, stream>>>(ei, E, flagI, cnt);
    alloc_kernel<<<(N + 255) / 256, 256, 0, stream>>>(cnt, rowstart, cursor, dis, head, N);
    fill_kernel <<<(E + 255) / 256, 256, 0, stream>>>(ei, E, flagI, cursor, csr);
    swizzle_w   <<<16, 256, 0, stream>>>(W1, W2, Wsw1, Wsw2);

    int tiles   = (N + 15) / 16;
    int gblocks = (tiles + 3) / 4;          // 782
    int ablocks = (N + 3) / 4;              // 12500

    // layer 1 (cast fused into the gemm: reads f32 x directly)
    gemm_mfma<true><<<gblocks, 256, 0, stream>>>(x, Wsw1, dis, ybuf, N);
    aggregate_bf<false><<<ablocks, 256, 0, stream>>>((const unsigned*)ybuf, rowstart, cnt,
                                                     csr, dis, b1, (unsigned*)hbuf, nullptr, N);
    // layer 2
    gemm_mfma<false><<<gblocks, 256, 0, stream>>>(hbuf, Wsw2, dis, ybuf, N);
    aggregate_bf<true><<<ablocks, 256, 0, stream>>>((const unsigned*)ybuf, rowstart, cnt,
                                                    csr, dis, b2, nullptr, (float2*)d_out, N);
}